// Round 11
// baseline (851.898 us; speedup 1.0000x reference)
//
#include <hip/hip_runtime.h>
#include <math.h>

#define NPTS 8192
#define NB   16
#define NG   512
#define KNN  32

typedef float v2f __attribute__((ext_vector_type(2)));

// Packed f32 VOP3P helpers — IEEE per-component, bit-identical to scalar ops.
// (Used only in knn_kernel.)
__device__ __forceinline__ v2f pk_add(v2f a, v2f b) {
    v2f r; asm("v_pk_add_f32 %0, %1, %2" : "=v"(r) : "v"(a), "v"(b)); return r;
}
__device__ __forceinline__ v2f pk_mul(v2f a, v2f b) {
    v2f r; asm("v_pk_mul_f32 %0, %1, %2" : "=v"(r) : "v"(a), "v"(b)); return r;
}
__device__ __forceinline__ v2f pk_fma(v2f a, v2f b, v2f c) {
    v2f r; asm("v_pk_fma_f32 %0, %1, %2, %3" : "=v"(r) : "v"(a), "v"(b), "v"(c)); return r;
}

// ---- DPP wave64 max chain (VALU pipe, no LDS unit) -------------------------
#define DPP_MAXF(v, ctrl)                                                       \
    v = fmaxf(v, __int_as_float(__builtin_amdgcn_update_dpp(                    \
            0, __float_as_int(v), (ctrl), 0xF, 0xF, true)))

__device__ __forceinline__ float max3f(float a, float b, float c) {
    return fmaxf(fmaxf(a, b), c);   // clang fuses to v_max3_f32
}

// ---------------- FPS: one block/batch, 256 threads, 32 pts/thread ---------
// Inner loop: value-only min update (no selects). Lane max via max3 tree.
// Index recovered scalar-side: 32 ballots + SALU first-match scan (exact
// smallest-global-index tie-break). Winner coords ride the cross-wave
// exchange (parallel reads + cndmask select, no dependent LDS lookup).
__global__ __launch_bounds__(256) void fps_kernel(const float* __restrict__ xyz,
                                                  int* __restrict__ fidx)
{
#pragma clang fp contract(off)
    __shared__ float s_xyz[NPTS * 3];                 // 96 KB
    __shared__ unsigned long long skey[2][4];
    __shared__ __align__(16) float scoord[2][12];     // [buf][wave*3+c]

    const int b    = blockIdx.x;
    const int t    = threadIdx.x;                     // 0..255
    const int w    = t >> 6;
    const int lane = t & 63;
    const float* base = xyz + (size_t)b * NPTS * 3;

    for (int j = t; j < NPTS * 3 / 4; j += 256)
        ((float4*)s_xyz)[j] = ((const float4*)base)[j];
    __syncthreads();

    // lane owns points p = t + 256*slot, slot = 0..31  (p = 256*j + t: j-major)
    float px[32], py[32], pz[32], dd[32];
#pragma unroll
    for (int j = 0; j < 32; ++j) {
        int p = t + (j << 8);
        px[j] = s_xyz[3*p+0];
        py[j] = s_xyz[3*p+1];
        pz[j] = s_xyz[3*p+2];
        dd[j] = INFINITY;
    }
    if (t == 0) fidx[b*NG] = 0;

    float cx = s_xyz[0], cy = s_xyz[1], cz = s_xyz[2];

    for (int it = 1; it < NG; ++it) {
        const int s = it & 1;

        // ---- phase 1: distance + running-min only (no selects, full ILP) ----
#pragma unroll
        for (int j = 0; j < 32; ++j) {
            float dx = px[j]-cx, dy = py[j]-cy, dz = pz[j]-cz;
            float d  = (dx*dx + dy*dy) + dz*dz;   // match ref: (d0+d1)+d2, no fma
            dd[j] = fminf(dd[j], d);
        }

        // ---- phase 2: lane max via max3 tree (values only) ----
        float r0 = max3f(dd[0],  dd[1],  dd[2]);
        float r1 = max3f(dd[3],  dd[4],  dd[5]);
        float r2 = max3f(dd[6],  dd[7],  dd[8]);
        float r3 = max3f(dd[9],  dd[10], dd[11]);
        float r4 = max3f(dd[12], dd[13], dd[14]);
        float r5 = max3f(dd[15], dd[16], dd[17]);
        float r6 = max3f(dd[18], dd[19], dd[20]);
        float r7 = max3f(dd[21], dd[22], dd[23]);
        float r8 = max3f(dd[24], dd[25], dd[26]);
        float r9 = max3f(dd[27], dd[28], dd[29]);
        float ra = fmaxf(dd[30], dd[31]);
        float s0 = max3f(r0, r1, r2);
        float s1 = max3f(r3, r4, r5);
        float s2 = max3f(r6, r7, r8);
        float s3 = fmaxf(r9, ra);
        float bv = fmaxf(max3f(s0, s1, s2), s3);

        // ---- wave max via DPP ----
        float mv = bv;
        DPP_MAXF(mv, 0x111);  // row_shr:1
        DPP_MAXF(mv, 0x112);  // row_shr:2
        DPP_MAXF(mv, 0x114);  // row_shr:4
        DPP_MAXF(mv, 0x118);  // row_shr:8
        DPP_MAXF(mv, 0x142);  // row_bcast:15
        DPP_MAXF(mv, 0x143);  // row_bcast:31
        const unsigned Mbits = (unsigned)__builtin_amdgcn_readlane(__float_as_int(mv), 63);

        // ---- index recovery: 32 ballots (VALU) + uniform first-match scan
        //      (SALU, overlapped). First (j, lane) = smallest global index. ----
        unsigned long long acc = 0ull; int jw = 0;
#pragma unroll
        for (int j = 0; j < 32; ++j) {
            unsigned long long mj = __ballot(__float_as_uint(dd[j]) == Mbits);
            bool take = (acc == 0ull) & (mj != 0ull);
            acc = take ? mj : acc;
            jw  = take ? j : jw;
        }
        const unsigned wIdx = ((unsigned)jw << 8) | ((unsigned)w << 6)
                            | (unsigned)(__ffsll((unsigned long long)acc) - 1);

        // ---- exchange: key + candidate coords (coords read pre-barrier) ----
        if (lane == 0) {
            float wx = s_xyz[3*wIdx+0];
            float wy = s_xyz[3*wIdx+1];
            float wz = s_xyz[3*wIdx+2];
            skey[s][w] = ((unsigned long long)Mbits << 32) | (unsigned)(8191 - wIdx);
            scoord[s][w*3+0] = wx;
            scoord[s][w*3+1] = wy;
            scoord[s][w*3+2] = wz;
        }
        __syncthreads();

        // parallel reads: 4 keys + 12 coords (independent addresses)
        ulonglong2 k01 = *(const ulonglong2*)&skey[s][0];
        ulonglong2 k23 = *(const ulonglong2*)&skey[s][2];
        float4 q0 = *(const float4*)&scoord[s][0];
        float4 q1 = *(const float4*)&scoord[s][4];
        float4 q2 = *(const float4*)&scoord[s][8];
        // wave w coords: w0=(q0.x,q0.y,q0.z) w1=(q0.w,q1.x,q1.y)
        //                w2=(q1.z,q1.w,q2.x) w3=(q2.y,q2.z,q2.w)
        bool s01 = (k01.y > k01.x);
        unsigned long long kA = s01 ? k01.y : k01.x;
        float ax = s01 ? q0.w : q0.x;
        float ay = s01 ? q1.x : q0.y;
        float az = s01 ? q1.y : q0.z;
        bool s23 = (k23.y > k23.x);
        unsigned long long kB = s23 ? k23.y : k23.x;
        float bx = s23 ? q2.y : q1.z;
        float by = s23 ? q2.z : q1.w;
        float bz = s23 ? q2.w : q2.x;
        bool sF = (kB > kA);
        unsigned long long km = sF ? kB : kA;
        cx = sF ? bx : ax;
        cy = sF ? by : ay;
        cz = sF ? bz : az;
        if (t == 0) fidx[b*NG + it] = 8191 - (int)(km & 0xFFFFu);
    }
}

// ---------------- KNN + gather: 16 waves/block, batch staged SoA in LDS -----
// Exact top-32 via threshold-select (T_ub = 32nd-smallest of 64 lane-minima);
// scans read LDS SoA via float2 (conflict-free); packed distance math.
__global__ __launch_bounds__(1024) void knn_kernel(const float* __restrict__ xyz,
                                                   const float* __restrict__ gtp,
                                                   const int* __restrict__ labels,
                                                   const int* __restrict__ fidx,
                                                   float* __restrict__ out)
{
#pragma clang fp contract(off)
    __shared__ float spx[NPTS], spy[NPTS], spz[NPTS];   // 96 KB SoA
    __shared__ float sdl[16][64];
    __shared__ int   sil[16][64];

    const int tb   = threadIdx.x;                        // 0..1023
    const int lane = tb & 63;
    const int w    = tb >> 6;                            // 0..15
    const int gid  = (blockIdx.x << 4) + w;              // 0..8191
    const int b    = gid >> 9;                           // same for whole block

    const float* base  = xyz + (size_t)b * NPTS * 3;
    const float* gbase = gtp + (size_t)b * NPTS * 3;

    // stage AoS -> SoA
    for (int j = tb; j < NPTS * 3 / 4; j += 1024) {
        float4 v = ((const float4*)base)[j];
        int f0 = 4*j;
#pragma unroll
        for (int e = 0; e < 4; ++e) {
            int f = f0 + e;
            float val = (e==0) ? v.x : (e==1) ? v.y : (e==2) ? v.z : v.w;
            int p = f / 3;
            int c = f - 3*p;
            float* dst = (c==0) ? spx : (c==1) ? spy : spz;
            dst[p] = val;
        }
    }
    __syncthreads();

    const int   cidx = fidx[gid];
    const float cx = spx[cidx], cy = spy[cidx], cz = spz[cidx];
    const float c2 = (cx*cx + cy*cy) + cz*cz;            // elementwise+reduce: no fma
    const v2f cx2 = (v2f){cx,cx}, cy2 = (v2f){cy,cy}, cz2 = (v2f){cz,cz};
    const v2f c22 = (v2f){c2,c2}, mm2 = (v2f){-2.0f,-2.0f};
    const unsigned long long lmask = (lane == 63) ? ~0ull >> 1 : (1ull << lane) - 1ull;

    // ---- scan 1: per-lane running min (2 pts/step via LDS float2) ----
    float m = INFINITY;
#pragma unroll 4
    for (int i = 0; i < 64; ++i) {
        int q = 2*lane + (i << 7);
        v2f xv = *(const v2f*)&spx[q];
        v2f yv = *(const v2f*)&spy[q];
        v2f zv = *(const v2f*)&spz[q];
        v2f p2 = pk_add(pk_add(pk_mul(xv,xv), pk_mul(yv,yv)), pk_mul(zv,zv)); // (x²+y²)+z²
        v2f cp = pk_fma(cz2, zv, pk_fma(cy2, yv, pk_mul(cx2, xv)));           // fma chain
        v2f dv = pk_add(pk_add(c22, p2), pk_mul(cp, mm2));                    // (c2+p2)-2cp
        m = fminf(m, dv.x);
        m = fminf(m, dv.y);
    }

    // ---- bitonic sort 64 lane-minima -> T_ub = 32nd smallest ----
    {
        float v = m;
#pragma unroll
        for (int k = 2; k <= 64; k <<= 1) {
#pragma unroll
            for (int j = k >> 1; j >= 1; j >>= 1) {
                float o = __shfl_xor(v, j);
                bool keep_min = (((lane & j) == 0) != ((lane & k) != 0));
                v = keep_min ? fminf(v, o) : fmaxf(v, o);
            }
        }
        m = __shfl(v, 31);
    }
    const float T_ub = m;

    // ---- scan 2: ballot-compact candidates d <= T_ub ----
    int cnt = 0;
    for (int i = 0; i < 64; ++i) {
        int q = 2*lane + (i << 7);
        v2f xv = *(const v2f*)&spx[q];
        v2f yv = *(const v2f*)&spy[q];
        v2f zv = *(const v2f*)&spz[q];
        v2f p2 = pk_add(pk_add(pk_mul(xv,xv), pk_mul(yv,yv)), pk_mul(zv,zv));
        v2f cp = pk_fma(cz2, zv, pk_fma(cy2, yv, pk_mul(cx2, xv)));
        v2f dv = pk_add(pk_add(c22, p2), pk_mul(cp, mm2));
        bool t0 = (dv.x <= T_ub);
        unsigned long long m0 = __ballot(t0);
        if (t0) {
            int slot = cnt + __popcll(m0 & lmask);
            if (slot < 64) { sdl[w][slot] = dv.x; sil[w][slot] = q; }
        }
        cnt += __popcll(m0);
        bool t1 = (dv.y <= T_ub);
        unsigned long long m1 = __ballot(t1);
        if (t1) {
            int slot = cnt + __popcll(m1 & lmask);
            if (slot < 64) { sdl[w][slot] = dv.y; sil[w][slot] = q + 1; }
        }
        cnt += __popcll(m1);
    }

    int myIdx = 0;
    if (cnt <= 64) {
        // ---- fast path: 64-lane bitonic sort of (d, idx) pairs ----
        float d  = (lane < cnt) ? sdl[w][lane] : INFINITY;
        int   ix = (lane < cnt) ? sil[w][lane] : 0x7fffffff;
#pragma unroll
        for (int k = 2; k <= 64; k <<= 1) {
#pragma unroll
            for (int j = k >> 1; j >= 1; j >>= 1) {
                float od = __shfl_xor(d, j);
                int   oi = __shfl_xor(ix, j);
                bool keep_min = (((lane & j) == 0) != ((lane & k) != 0));
                bool o_less   = (od < d) || (od == d && oi < ix);
                bool take_o   = keep_min ? o_less : !o_less;
                if (take_o) { d = od; ix = oi; }
            }
        }
        myIdx = ix;                                 // lane r holds rank r
    } else {
        // ---- exact fallback (rare): per-lane sorted top-32 + merge ----
        float ld[KNN]; int li[KNN];
#pragma unroll
        for (int j = 0; j < KNN; ++j) { ld[j] = INFINITY; li[j] = 0x7fffffff; }
        for (int i = 0; i < NPTS/64; ++i) {
            int p = lane + (i << 6);
            float x = spx[p], y = spy[p], z = spz[p];
            float p2 = (x*x + y*y) + z*z;
            float cp = fmaf(cz, z, fmaf(cy, y, cx*x));
            float d  = (c2 + p2) - 2.0f*cp;
            if (d < ld[KNN-1]) {
                float cv = d; int ci = p;
#pragma unroll
                for (int j = 0; j < KNN; ++j) {
                    if (cv < ld[j]) {
                        float tv = ld[j]; int ti = li[j];
                        ld[j] = cv; li[j] = ci;
                        cv = tv; ci = ti;
                    }
                }
            }
        }
#pragma unroll
        for (int r = 0; r < KNN; ++r) {
            float bv = ld[0]; int bi = li[0]; int bl = lane;
#pragma unroll
            for (int off = 32; off >= 1; off >>= 1) {
                float ov = __shfl_xor(bv, off);
                int   oi = __shfl_xor(bi, off);
                int   ol = __shfl_xor(bl, off);
                if (ov < bv || (ov == bv && oi < bi)) { bv = ov; bi = oi; bl = ol; }
            }
            if (lane == r) myIdx = bi;
            if (lane == bl) {
#pragma unroll
                for (int j = 0; j < KNN-1; ++j) { ld[j] = ld[j+1]; li[j] = li[j+1]; }
                ld[KNN-1] = INFINITY; li[KNN-1] = 0x7fffffff;
            }
        }
    }

    // outputs (flat concat): neighborhood | center | gt_neighborhood | grp_labels
    float* out_nb  = out;                          // 786432
    float* out_c   = out + 786432;                 // 24576
    float* out_gnb = out + 811008;                 // 786432
    float* out_lb  = out + 1597440;                // 262144

    const float gcx = gbase[3*cidx+0], gcy = gbase[3*cidx+1], gcz = gbase[3*cidx+2];

    if (lane < KNN) {
        int p = myIdx;
        size_t o3 = ((size_t)gid * KNN + lane) * 3;
        out_nb[o3+0]  = spx[p] - cx;
        out_nb[o3+1]  = spy[p] - cy;
        out_nb[o3+2]  = spz[p] - cz;
        out_gnb[o3+0] = gbase[3*p+0] - gcx;
        out_gnb[o3+1] = gbase[3*p+1] - gcy;
        out_gnb[o3+2] = gbase[3*p+2] - gcz;
        out_lb[(size_t)gid*KNN + lane] = (float)labels[(size_t)b*NPTS + p];
    }
    if (lane == 0) {
        out_c[gid*3+0] = cx; out_c[gid*3+1] = cy; out_c[gid*3+2] = cz;
    }
}

extern "C" void kernel_launch(void* const* d_in, const int* in_sizes, int n_in,
                              void* d_out, int out_size, void* d_ws, size_t ws_size,
                              hipStream_t stream)
{
    const float* xyz    = (const float*)d_in[0];
    const float* gtp    = (const float*)d_in[1];
    const int*   labels = (const int*)d_in[2];
    int*   fidx = (int*)d_ws;
    float* outp = (float*)d_out;

    hipLaunchKernelGGL(fps_kernel, dim3(NB), dim3(256), 0, stream, xyz, fidx);
    hipLaunchKernelGGL(knn_kernel, dim3(NB*NG/16), dim3(1024), 0, stream,
                       xyz, gtp, labels, fidx, outp);
}

// Round 12
// 557.920 us; speedup vs baseline: 1.5269x; 1.5269x over previous
//
#include <hip/hip_runtime.h>
#include <math.h>

#define NPTS 8192
#define NB   16
#define NG   512
#define KNN  32

typedef float v2f __attribute__((ext_vector_type(2)));

// Packed f32 VOP3P helpers — IEEE per-component, bit-identical to scalar ops.
// (Used only in knn_kernel; FPS uses plain scalar ops for scheduler freedom.)
__device__ __forceinline__ v2f pk_add(v2f a, v2f b) {
    v2f r; asm("v_pk_add_f32 %0, %1, %2" : "=v"(r) : "v"(a), "v"(b)); return r;
}
__device__ __forceinline__ v2f pk_mul(v2f a, v2f b) {
    v2f r; asm("v_pk_mul_f32 %0, %1, %2" : "=v"(r) : "v"(a), "v"(b)); return r;
}
__device__ __forceinline__ v2f pk_fma(v2f a, v2f b, v2f c) {
    v2f r; asm("v_pk_fma_f32 %0, %1, %2, %3" : "=v"(r) : "v"(a), "v"(b), "v"(c)); return r;
}

// ---- DPP wave64 reduce steps (VALU pipe, no LDS unit) ----------------------
#define DPP_MAXF(v, ctrl)                                                       \
    v = fmaxf(v, __int_as_float(__builtin_amdgcn_update_dpp(                    \
            0, __float_as_int(v), (ctrl), 0xF, 0xF, true)))
#define DPP_MINU(v, ctrl)                                                       \
    {   unsigned _o = (unsigned)__builtin_amdgcn_update_dpp(                    \
            (int)0x7FFFFFFF, (int)(v), (ctrl), 0xF, 0xF, false);                \
        v = (v < _o) ? v : _o; }

// ---------------- FPS: one block/batch, 256 threads, 32 pts/thread ---------
// Round-10 structure (verified best): plain scalar inner loop with in-loop
// serial select; DPP value chain + ballot index fast path; u64-key exchange.
__global__ __launch_bounds__(256) void fps_kernel(const float* __restrict__ xyz,
                                                  int* __restrict__ fidx)
{
#pragma clang fp contract(off)
    __shared__ float s_xyz[NPTS * 3];                 // 96 KB
    __shared__ unsigned long long skey[2][4];

    const int b    = blockIdx.x;
    const int t    = threadIdx.x;                     // 0..255
    const int w    = t >> 6;
    const int lane = t & 63;
    const float* base = xyz + (size_t)b * NPTS * 3;

    for (int j = t; j < NPTS * 3 / 4; j += 256)
        ((float4*)s_xyz)[j] = ((const float4*)base)[j];
    __syncthreads();

    // lane owns points p = t + 256*slot, slot = 0..31
    float px[32], py[32], pz[32], dd[32];
#pragma unroll
    for (int j = 0; j < 32; ++j) {
        int p = t + (j << 8);
        px[j] = s_xyz[3*p+0];
        py[j] = s_xyz[3*p+1];
        pz[j] = s_xyz[3*p+2];
        dd[j] = INFINITY;
    }
    if (t == 0) fidx[b*NG] = 0;

    float cx = s_xyz[0], cy = s_xyz[1], cz = s_xyz[2];

    for (int it = 1; it < NG; ++it) {
        const int s = it & 1;
        float bv = -INFINITY; int sl = 0;
#pragma unroll
        for (int j = 0; j < 32; ++j) {
            float dx = px[j]-cx, dy = py[j]-cy, dz = pz[j]-cz;
            float d  = (dx*dx + dy*dy) + dz*dz;   // match ref: (d0+d1)+d2, no fma
            float nd = fminf(dd[j], d);
            dd[j] = nd;
            if (nd > bv) { bv = nd; sl = j; }     // strict >: smallest idx on tie
        }
        const int bi = t + (sl << 8);

        // ---- intra-wave argmax: DPP value chain + ballot index fast path ----
        float mv = bv;
        DPP_MAXF(mv, 0x111);  // row_shr:1
        DPP_MAXF(mv, 0x112);  // row_shr:2
        DPP_MAXF(mv, 0x114);  // row_shr:4
        DPP_MAXF(mv, 0x118);  // row_shr:8
        DPP_MAXF(mv, 0x142);  // row_bcast:15
        DPP_MAXF(mv, 0x143);  // row_bcast:31
        const unsigned Mbits = (unsigned)__builtin_amdgcn_readlane(__float_as_int(mv), 63);

        unsigned long long mask = __ballot(__float_as_uint(bv) == Mbits);
        unsigned wIdx;
        if (__popcll(mask) == 1) {
            // unique max lane; its bi is already the first occurrence
            wIdx = (unsigned)__builtin_amdgcn_readlane(bi, (int)__ffsll(mask) - 1);
        } else {
            // exact tie-break: min global index among max-valued lanes
            unsigned cand = (__float_as_uint(bv) == Mbits) ? (unsigned)bi : 0x7FFFFFFFu;
            DPP_MINU(cand, 0x111);
            DPP_MINU(cand, 0x112);
            DPP_MINU(cand, 0x114);
            DPP_MINU(cand, 0x118);
            DPP_MINU(cand, 0x142);
            DPP_MINU(cand, 0x143);
            wIdx = (unsigned)__builtin_amdgcn_readlane((int)cand, 63);
        }

        // key: d bits (d>=0 -> order-preserving) | (8191-idx): max -> max d, tie -> min idx
        if (lane == 0)
            skey[s][w] = ((unsigned long long)Mbits << 32) | (unsigned)(8191 - wIdx);
        __syncthreads();
        unsigned long long km = skey[s][0];
        km = (skey[s][1] > km) ? skey[s][1] : km;
        km = (skey[s][2] > km) ? skey[s][2] : km;
        km = (skey[s][3] > km) ? skey[s][3] : km;
        const int ix = 8191 - (int)(km & 0xFFFFu);
        cx = s_xyz[3*ix+0]; cy = s_xyz[3*ix+1]; cz = s_xyz[3*ix+2];
        if (t == 0) fidx[b*NG + it] = ix;
    }
}

// ---------------- KNN + gather: 16 waves/block, batch staged SoA in LDS -----
// Exact top-32 via threshold-select (T_ub = 32nd-smallest of 64 lane-minima);
// scans read LDS SoA via float2 (conflict-free); packed distance math.
__global__ __launch_bounds__(1024) void knn_kernel(const float* __restrict__ xyz,
                                                   const float* __restrict__ gtp,
                                                   const int* __restrict__ labels,
                                                   const int* __restrict__ fidx,
                                                   float* __restrict__ out)
{
#pragma clang fp contract(off)
    __shared__ float spx[NPTS], spy[NPTS], spz[NPTS];   // 96 KB SoA
    __shared__ float sdl[16][64];
    __shared__ int   sil[16][64];

    const int tb   = threadIdx.x;                        // 0..1023
    const int lane = tb & 63;
    const int w    = tb >> 6;                            // 0..15
    const int gid  = (blockIdx.x << 4) + w;              // 0..8191
    const int b    = gid >> 9;                           // same for whole block

    const float* base  = xyz + (size_t)b * NPTS * 3;
    const float* gbase = gtp + (size_t)b * NPTS * 3;

    // stage AoS -> SoA
    for (int j = tb; j < NPTS * 3 / 4; j += 1024) {
        float4 v = ((const float4*)base)[j];
        int f0 = 4*j;
#pragma unroll
        for (int e = 0; e < 4; ++e) {
            int f = f0 + e;
            float val = (e==0) ? v.x : (e==1) ? v.y : (e==2) ? v.z : v.w;
            int p = f / 3;
            int c = f - 3*p;
            float* dst = (c==0) ? spx : (c==1) ? spy : spz;
            dst[p] = val;
        }
    }
    __syncthreads();

    const int   cidx = fidx[gid];
    const float cx = spx[cidx], cy = spy[cidx], cz = spz[cidx];
    const float c2 = (cx*cx + cy*cy) + cz*cz;            // elementwise+reduce: no fma
    const v2f cx2 = (v2f){cx,cx}, cy2 = (v2f){cy,cy}, cz2 = (v2f){cz,cz};
    const v2f c22 = (v2f){c2,c2}, mm2 = (v2f){-2.0f,-2.0f};
    const unsigned long long lmask = (lane == 63) ? ~0ull >> 1 : (1ull << lane) - 1ull;

    // ---- scan 1: per-lane running min (2 pts/step via LDS float2) ----
    float m = INFINITY;
#pragma unroll 4
    for (int i = 0; i < 64; ++i) {
        int q = 2*lane + (i << 7);
        v2f xv = *(const v2f*)&spx[q];
        v2f yv = *(const v2f*)&spy[q];
        v2f zv = *(const v2f*)&spz[q];
        v2f p2 = pk_add(pk_add(pk_mul(xv,xv), pk_mul(yv,yv)), pk_mul(zv,zv)); // (x²+y²)+z²
        v2f cp = pk_fma(cz2, zv, pk_fma(cy2, yv, pk_mul(cx2, xv)));           // fma chain
        v2f dv = pk_add(pk_add(c22, p2), pk_mul(cp, mm2));                    // (c2+p2)-2cp
        m = fminf(m, dv.x);
        m = fminf(m, dv.y);
    }

    // ---- bitonic sort 64 lane-minima -> T_ub = 32nd smallest ----
    {
        float v = m;
#pragma unroll
        for (int k = 2; k <= 64; k <<= 1) {
#pragma unroll
            for (int j = k >> 1; j >= 1; j >>= 1) {
                float o = __shfl_xor(v, j);
                bool keep_min = (((lane & j) == 0) != ((lane & k) != 0));
                v = keep_min ? fminf(v, o) : fmaxf(v, o);
            }
        }
        m = __shfl(v, 31);
    }
    const float T_ub = m;

    // ---- scan 2: ballot-compact candidates d <= T_ub ----
    int cnt = 0;
    for (int i = 0; i < 64; ++i) {
        int q = 2*lane + (i << 7);
        v2f xv = *(const v2f*)&spx[q];
        v2f yv = *(const v2f*)&spy[q];
        v2f zv = *(const v2f*)&spz[q];
        v2f p2 = pk_add(pk_add(pk_mul(xv,xv), pk_mul(yv,yv)), pk_mul(zv,zv));
        v2f cp = pk_fma(cz2, zv, pk_fma(cy2, yv, pk_mul(cx2, xv)));
        v2f dv = pk_add(pk_add(c22, p2), pk_mul(cp, mm2));
        bool t0 = (dv.x <= T_ub);
        unsigned long long m0 = __ballot(t0);
        if (t0) {
            int slot = cnt + __popcll(m0 & lmask);
            if (slot < 64) { sdl[w][slot] = dv.x; sil[w][slot] = q; }
        }
        cnt += __popcll(m0);
        bool t1 = (dv.y <= T_ub);
        unsigned long long m1 = __ballot(t1);
        if (t1) {
            int slot = cnt + __popcll(m1 & lmask);
            if (slot < 64) { sdl[w][slot] = dv.y; sil[w][slot] = q + 1; }
        }
        cnt += __popcll(m1);
    }

    int myIdx = 0;
    if (cnt <= 64) {
        // ---- fast path: 64-lane bitonic sort of (d, idx) pairs ----
        float d  = (lane < cnt) ? sdl[w][lane] : INFINITY;
        int   ix = (lane < cnt) ? sil[w][lane] : 0x7fffffff;
#pragma unroll
        for (int k = 2; k <= 64; k <<= 1) {
#pragma unroll
            for (int j = k >> 1; j >= 1; j >>= 1) {
                float od = __shfl_xor(d, j);
                int   oi = __shfl_xor(ix, j);
                bool keep_min = (((lane & j) == 0) != ((lane & k) != 0));
                bool o_less   = (od < d) || (od == d && oi < ix);
                bool take_o   = keep_min ? o_less : !o_less;
                if (take_o) { d = od; ix = oi; }
            }
        }
        myIdx = ix;                                 // lane r holds rank r
    } else {
        // ---- exact fallback (rare): per-lane sorted top-32 + merge ----
        float ld[KNN]; int li[KNN];
#pragma unroll
        for (int j = 0; j < KNN; ++j) { ld[j] = INFINITY; li[j] = 0x7fffffff; }
        for (int i = 0; i < NPTS/64; ++i) {
            int p = lane + (i << 6);
            float x = spx[p], y = spy[p], z = spz[p];
            float p2 = (x*x + y*y) + z*z;
            float cp = fmaf(cz, z, fmaf(cy, y, cx*x));
            float d  = (c2 + p2) - 2.0f*cp;
            if (d < ld[KNN-1]) {
                float cv = d; int ci = p;
#pragma unroll
                for (int j = 0; j < KNN; ++j) {
                    if (cv < ld[j]) {
                        float tv = ld[j]; int ti = li[j];
                        ld[j] = cv; li[j] = ci;
                        cv = tv; ci = ti;
                    }
                }
            }
        }
#pragma unroll
        for (int r = 0; r < KNN; ++r) {
            float bv = ld[0]; int bi = li[0]; int bl = lane;
#pragma unroll
            for (int off = 32; off >= 1; off >>= 1) {
                float ov = __shfl_xor(bv, off);
                int   oi = __shfl_xor(bi, off);
                int   ol = __shfl_xor(bl, off);
                if (ov < bv || (ov == bv && oi < bi)) { bv = ov; bi = oi; bl = ol; }
            }
            if (lane == r) myIdx = bi;
            if (lane == bl) {
#pragma unroll
                for (int j = 0; j < KNN-1; ++j) { ld[j] = ld[j+1]; li[j] = li[j+1]; }
                ld[KNN-1] = INFINITY; li[KNN-1] = 0x7fffffff;
            }
        }
    }

    // outputs (flat concat): neighborhood | center | gt_neighborhood | grp_labels
    float* out_nb  = out;                          // 786432
    float* out_c   = out + 786432;                 // 24576
    float* out_gnb = out + 811008;                 // 786432
    float* out_lb  = out + 1597440;                // 262144

    const float gcx = gbase[3*cidx+0], gcy = gbase[3*cidx+1], gcz = gbase[3*cidx+2];

    if (lane < KNN) {
        int p = myIdx;
        size_t o3 = ((size_t)gid * KNN + lane) * 3;
        out_nb[o3+0]  = spx[p] - cx;
        out_nb[o3+1]  = spy[p] - cy;
        out_nb[o3+2]  = spz[p] - cz;
        out_gnb[o3+0] = gbase[3*p+0] - gcx;
        out_gnb[o3+1] = gbase[3*p+1] - gcy;
        out_gnb[o3+2] = gbase[3*p+2] - gcz;
        out_lb[(size_t)gid*KNN + lane] = (float)labels[(size_t)b*NPTS + p];
    }
    if (lane == 0) {
        out_c[gid*3+0] = cx; out_c[gid*3+1] = cy; out_c[gid*3+2] = cz;
    }
}

extern "C" void kernel_launch(void* const* d_in, const int* in_sizes, int n_in,
                              void* d_out, int out_size, void* d_ws, size_t ws_size,
                              hipStream_t stream)
{
    const float* xyz    = (const float*)d_in[0];
    const float* gtp    = (const float*)d_in[1];
    const int*   labels = (const int*)d_in[2];
    int*   fidx = (int*)d_ws;
    float* outp = (float*)d_out;

    hipLaunchKernelGGL(fps_kernel, dim3(NB), dim3(256), 0, stream, xyz, fidx);
    hipLaunchKernelGGL(knn_kernel, dim3(NB*NG/16), dim3(1024), 0, stream,
                       xyz, gtp, labels, fidx, outp);
}